// Round 1
// baseline (1062.815 us; speedup 1.0000x reference)
//
#include <hip/hip_runtime.h>
#include <hip/hip_bf16.h>

// Sizes (fixed by the problem)
//   B=2048, C=16, L=3, D=128, H=128, ED=8, T=4
//   N = [2048, 32768, 524288]
#define WX_STRIDE (132*128)   // 16896 floats per level in W_x

__device__ __forceinline__ float tanh_fast(float x) {
    // exact identity: tanh(x) = 1 - 2/(exp(2x)+1); stable at +/-inf
    return 1.f - 2.f / (__expf(2.f * x) + 1.f);
}
__device__ __forceinline__ float sigmoid_fast(float x) {
    return 1.f / (1.f + __expf(-x));
}

// ---------------------------------------------------------------------------
// prep: Wc[l] = W_fe @ W_x[l][:128,:]   (fold feature-extract into rnn weight)
//       bb[l] = b_fe @ W_x[l][:128,:] + b_r[l]
// grid (3, 129) x 128 threads; blockIdx.y==128 computes the bias row.
// ---------------------------------------------------------------------------
__global__ __launch_bounds__(128)
void prep_kernel(const float* __restrict__ W_fe, const float* __restrict__ b_fe,
                 const float* __restrict__ W_x, const float* __restrict__ b_r,
                 float* __restrict__ Wc, float* __restrict__ bb)
{
    const int l = blockIdx.x;
    const int d = blockIdx.y;          // 0..127 weight row, 128 => bias
    const int h = threadIdx.x;
    const float* wx = W_x + l * WX_STRIDE;
    if (d < 128) {
        const float* fer = W_fe + d * 128;
        float s = 0.f;
        for (int k = 0; k < 128; ++k) s = fmaf(fer[k], wx[k*128 + h], s);
        Wc[l*16384 + d*128 + h] = s;
    } else {
        float s = b_r[l*128 + h];
        for (int k = 0; k < 128; ++k) s = fmaf(b_fe[k], wx[k*128 + h], s);
        bb[l*128 + h] = s;
    }
}

// ---------------------------------------------------------------------------
// gnn_kernel: one parent per 64-thread block; thread owns cols (2t, 2t+1).
// COMPUTE_CH=true : children hiddens computed in-block from leaf inputs
//                   ch[c] = tanh(x2[child] @ Wc2 + bb2 + typerow)   (leaf rnn)
// COMPUTE_CH=false: children hiddens loaded from global (h1)
// then: g = sigmoid(E . We); w = A*g; M = w @ ch; Hc = relu(M @ Wg + bg);
//       pooled[p] = max_c Hc
// ---------------------------------------------------------------------------
template<bool COMPUTE_CH>
__global__ __launch_bounds__(64)
void gnn_kernel(const float* __restrict__ xc,   // x2 (leaf inputs) or h1
                const int*   __restrict__ tc,   // t2 or nullptr
                const float* __restrict__ A,    // [P,16,16]
                const float* __restrict__ E,    // [P,16,16,8]
                const float* __restrict__ We,   // [8]
                const float* __restrict__ Wg,   // [128,128]
                const float* __restrict__ bg,   // [128]
                const float* __restrict__ Wcl,  // fused leaf weight (or null)
                const float* __restrict__ bbl,  // fused leaf bias (or null)
                const float* __restrict__ WxT,  // leaf type rows (or null)
                float* __restrict__ pooled)     // [P,128]
{
    __shared__ __align__(16) float buf[16*128];   // x-tile, then M-tile
    __shared__ __align__(16) float wmat[256];     // gated adjacency
    const int p = blockIdx.x;
    const int t = threadIdx.x;
    const int c0 = 2*t, c1 = 2*t + 1;

    float2 ch[16];

    if (COMPUTE_CH) {
        // stage the 16 children input rows
        const float4* xg4 = (const float4*)(xc + (size_t)p * (16*128));
        float4* buf4 = (float4*)buf;
        #pragma unroll
        for (int i = t; i < 16*32; i += 64) buf4[i] = xg4[i];
        __syncthreads();

        float2 acc[16];
        #pragma unroll
        for (int c = 0; c < 16; ++c) {
            const int ty = tc[p*16 + c];
            const float* trw = WxT + ty*128;
            acc[c].x = bbl[c0] + trw[c0];
            acc[c].y = bbl[c1] + trw[c1];
        }
        const float2* W2 = (const float2*)Wcl;
        for (int d0 = 0; d0 < 128; d0 += 4) {
            const float2 w0 = W2[(d0+0)*64 + t];
            const float2 w1 = W2[(d0+1)*64 + t];
            const float2 w2 = W2[(d0+2)*64 + t];
            const float2 w3 = W2[(d0+3)*64 + t];
            const float4* xv4 = (const float4*)buf + (d0 >> 2);
            #pragma unroll
            for (int c = 0; c < 16; ++c) {
                const float4 xv = xv4[c*32];   // wave-uniform broadcast
                acc[c].x = fmaf(xv.x, w0.x, acc[c].x);
                acc[c].y = fmaf(xv.x, w0.y, acc[c].y);
                acc[c].x = fmaf(xv.y, w1.x, acc[c].x);
                acc[c].y = fmaf(xv.y, w1.y, acc[c].y);
                acc[c].x = fmaf(xv.z, w2.x, acc[c].x);
                acc[c].y = fmaf(xv.z, w2.y, acc[c].y);
                acc[c].x = fmaf(xv.w, w3.x, acc[c].x);
                acc[c].y = fmaf(xv.w, w3.y, acc[c].y);
            }
        }
        #pragma unroll
        for (int c = 0; c < 16; ++c) {
            ch[c].x = tanh_fast(acc[c].x);
            ch[c].y = tanh_fast(acc[c].y);
        }
    } else {
        #pragma unroll
        for (int c = 0; c < 16; ++c) {
            const float2* hp = (const float2*)(xc + ((size_t)p*16 + c) * 128);
            ch[c] = hp[t];
        }
    }

    // edge gating: wmat[c*16+k] = A[p,c,k] * sigmoid(E[p,c,k,:] . We)
    {
        const float4* Ep = (const float4*)(E + (size_t)p * 2048);
        const float*  Ap = A + (size_t)p * 256;
        const float we0=We[0], we1=We[1], we2=We[2], we3=We[3];
        const float we4=We[4], we5=We[5], we6=We[6], we7=We[7];
        #pragma unroll
        for (int j = 0; j < 4; ++j) {
            const int q = 4*t + j;
            const float4 e0 = Ep[2*q];
            const float4 e1 = Ep[2*q + 1];
            float z = e0.x*we0 + e0.y*we1 + e0.z*we2 + e0.w*we3
                    + e1.x*we4 + e1.y*we5 + e1.z*we6 + e1.w*we7;
            wmat[q] = Ap[q] * sigmoid_fast(z);
        }
    }
    __syncthreads();

    // M[c][h] = sum_k wmat[c][k] * ch[k][h]  (ch columns live in registers)
    float2 m[16];
    const float4* wm4 = (const float4*)wmat;
    #pragma unroll
    for (int c = 0; c < 16; ++c) {
        float mx = 0.f, my = 0.f;
        #pragma unroll
        for (int k4 = 0; k4 < 4; ++k4) {
            const float4 w = wm4[c*4 + k4];
            mx = fmaf(w.x, ch[4*k4+0].x, mx); my = fmaf(w.x, ch[4*k4+0].y, my);
            mx = fmaf(w.y, ch[4*k4+1].x, mx); my = fmaf(w.y, ch[4*k4+1].y, my);
            mx = fmaf(w.z, ch[4*k4+2].x, mx); my = fmaf(w.z, ch[4*k4+2].y, my);
            mx = fmaf(w.w, ch[4*k4+3].x, mx); my = fmaf(w.w, ch[4*k4+3].y, my);
        }
        m[c].x = mx; m[c].y = my;
    }
    #pragma unroll
    for (int c = 0; c < 16; ++c) ((float2*)buf)[c*64 + t] = m[c];
    __syncthreads();

    // Hc = relu(M @ Wg + bg); pooled = max_c Hc = max(0, max_c (M@Wg+bg))
    float2 acc[16];
    #pragma unroll
    for (int c = 0; c < 16; ++c) { acc[c].x = bg[c0]; acc[c].y = bg[c1]; }
    const float2* Wg2 = (const float2*)Wg;
    for (int d0 = 0; d0 < 128; d0 += 4) {
        const float2 w0 = Wg2[(d0+0)*64 + t];
        const float2 w1 = Wg2[(d0+1)*64 + t];
        const float2 w2 = Wg2[(d0+2)*64 + t];
        const float2 w3 = Wg2[(d0+3)*64 + t];
        const float4* mv4 = (const float4*)buf + (d0 >> 2);
        #pragma unroll
        for (int c = 0; c < 16; ++c) {
            const float4 mv = mv4[c*32];
            acc[c].x = fmaf(mv.x, w0.x, acc[c].x);
            acc[c].y = fmaf(mv.x, w0.y, acc[c].y);
            acc[c].x = fmaf(mv.y, w1.x, acc[c].x);
            acc[c].y = fmaf(mv.y, w1.y, acc[c].y);
            acc[c].x = fmaf(mv.z, w2.x, acc[c].x);
            acc[c].y = fmaf(mv.z, w2.y, acc[c].y);
            acc[c].x = fmaf(mv.w, w3.x, acc[c].x);
            acc[c].y = fmaf(mv.w, w3.y, acc[c].y);
        }
    }
    float px = acc[0].x, py = acc[0].y;
    #pragma unroll
    for (int c = 1; c < 16; ++c) { px = fmaxf(px, acc[c].x); py = fmaxf(py, acc[c].y); }
    px = fmaxf(px, 0.f); py = fmaxf(py, 0.f);
    ((float2*)pooled)[(size_t)p*64 + t] = make_float2(px, py);
}

// ---------------------------------------------------------------------------
// rnn_kernel: out[r] = tanh(x[r] @ Wc[l] + pool[r] @ W_h[l] + bb[l] + typerow)
// R rows per 64-thread block; thread owns cols (2t, 2t+1).
// ---------------------------------------------------------------------------
template<int R>
__global__ __launch_bounds__(64)
void rnn_kernel(const float* __restrict__ x, const int* __restrict__ tt,
                const float* __restrict__ pool,
                const float* __restrict__ Wcl, const float* __restrict__ Whl,
                const float* __restrict__ bbl, const float* __restrict__ WxT,
                float* __restrict__ out)
{
    __shared__ __align__(16) float xs[R*128];
    __shared__ __align__(16) float ps[R*128];
    const int t = threadIdx.x;
    const int row0 = blockIdx.x * R;

    const float4* xg4 = (const float4*)(x + (size_t)row0 * 128);
    const float4* pg4 = (const float4*)(pool + (size_t)row0 * 128);
    float4* xs4w = (float4*)xs;
    float4* ps4w = (float4*)ps;
    #pragma unroll
    for (int i = t; i < R*32; i += 64) { xs4w[i] = xg4[i]; ps4w[i] = pg4[i]; }
    __syncthreads();

    const int c0 = 2*t, c1 = c0 + 1;
    float2 acc[R];
    #pragma unroll
    for (int r = 0; r < R; ++r) {
        const int ty = tt[row0 + r];
        const float* trw = WxT + ty*128;
        acc[r].x = bbl[c0] + trw[c0];
        acc[r].y = bbl[c1] + trw[c1];
    }
    const float2* W2 = (const float2*)Wcl;
    for (int d0 = 0; d0 < 128; d0 += 4) {
        const float2 w0 = W2[(d0+0)*64 + t];
        const float2 w1 = W2[(d0+1)*64 + t];
        const float2 w2 = W2[(d0+2)*64 + t];
        const float2 w3 = W2[(d0+3)*64 + t];
        const float4* xv4 = (const float4*)xs + (d0 >> 2);
        #pragma unroll
        for (int r = 0; r < R; ++r) {
            const float4 xv = xv4[r*32];
            acc[r].x = fmaf(xv.x, w0.x, acc[r].x);
            acc[r].y = fmaf(xv.x, w0.y, acc[r].y);
            acc[r].x = fmaf(xv.y, w1.x, acc[r].x);
            acc[r].y = fmaf(xv.y, w1.y, acc[r].y);
            acc[r].x = fmaf(xv.z, w2.x, acc[r].x);
            acc[r].y = fmaf(xv.z, w2.y, acc[r].y);
            acc[r].x = fmaf(xv.w, w3.x, acc[r].x);
            acc[r].y = fmaf(xv.w, w3.y, acc[r].y);
        }
    }
    const float2* Wh2 = (const float2*)Whl;
    for (int d0 = 0; d0 < 128; d0 += 4) {
        const float2 w0 = Wh2[(d0+0)*64 + t];
        const float2 w1 = Wh2[(d0+1)*64 + t];
        const float2 w2 = Wh2[(d0+2)*64 + t];
        const float2 w3 = Wh2[(d0+3)*64 + t];
        const float4* pv4 = (const float4*)ps + (d0 >> 2);
        #pragma unroll
        for (int r = 0; r < R; ++r) {
            const float4 pv = pv4[r*32];
            acc[r].x = fmaf(pv.x, w0.x, acc[r].x);
            acc[r].y = fmaf(pv.x, w0.y, acc[r].y);
            acc[r].x = fmaf(pv.y, w1.x, acc[r].x);
            acc[r].y = fmaf(pv.y, w1.y, acc[r].y);
            acc[r].x = fmaf(pv.z, w2.x, acc[r].x);
            acc[r].y = fmaf(pv.z, w2.y, acc[r].y);
            acc[r].x = fmaf(pv.w, w3.x, acc[r].x);
            acc[r].y = fmaf(pv.w, w3.y, acc[r].y);
        }
    }
    #pragma unroll
    for (int r = 0; r < R; ++r) {
        ((float2*)out)[(size_t)(row0 + r)*64 + t] =
            make_float2(tanh_fast(acc[r].x), tanh_fast(acc[r].y));
    }
}

// ---------------------------------------------------------------------------
extern "C" void kernel_launch(void* const* d_in, const int* in_sizes, int n_in,
                              void* d_out, int out_size, void* d_ws, size_t ws_size,
                              hipStream_t stream) {
    const float* x0   = (const float*)d_in[0];
    const float* x1   = (const float*)d_in[1];
    const float* x2   = (const float*)d_in[2];
    const int*   t0   = (const int*)d_in[3];
    const int*   t1   = (const int*)d_in[4];
    const int*   t2   = (const int*)d_in[5];
    const float* A0   = (const float*)d_in[6];
    const float* A1   = (const float*)d_in[7];
    const float* E0   = (const float*)d_in[8];
    const float* E1   = (const float*)d_in[9];
    const float* W_fe = (const float*)d_in[10];
    const float* b_fe = (const float*)d_in[11];
    const float* W_x  = (const float*)d_in[12];
    const float* W_h  = (const float*)d_in[13];
    const float* W_e  = (const float*)d_in[14];
    const float* W_g  = (const float*)d_in[15];
    const float* b_g  = (const float*)d_in[16];
    const float* b_r  = (const float*)d_in[17];
    float* out = (float*)d_out;

    // workspace layout (floats): Wc[3*128*128] | bb[3*128] | pooled1[32768*128]
    //                            | h1[32768*128] | pooled0[2048*128]  (~35 MB)
    float* ws      = (float*)d_ws;
    float* Wc      = ws;
    float* bb      = ws + 49152;
    float* pooled1 = ws + 49536;
    float* h1v     = pooled1 + 4194304;
    float* pooled0 = h1v + 4194304;

    // fold W_fe/b_fe into per-level rnn weights
    prep_kernel<<<dim3(3, 129), 128, 0, stream>>>(W_fe, b_fe, W_x, b_r, Wc, bb);

    // level 1: leaf rnn fused into per-parent GNN (h2 never materialized)
    gnn_kernel<true><<<32768, 64, 0, stream>>>(
        x2, t2, A1, E1,
        W_e + 8, W_g + 16384, b_g + 128,
        Wc + 2*16384, bb + 2*128, W_x + 2*WX_STRIDE + 16384,
        pooled1);

    // h1 = tanh(x1 @ Wc1 + pooled1 @ Wh1 + bb1 + typerow)
    rnn_kernel<8><<<32768/8, 64, 0, stream>>>(
        x1, t1, pooled1,
        Wc + 16384, W_h + 16384, bb + 128, W_x + WX_STRIDE + 16384,
        h1v);

    // level 0: GNN over root children (h1 loaded from global)
    gnn_kernel<false><<<2048, 64, 0, stream>>>(
        h1v, nullptr, A0, E0,
        W_e, W_g, b_g,
        nullptr, nullptr, nullptr,
        pooled0);

    // h0 = tanh(x0 @ Wc0 + pooled0 @ Wh0 + bb0 + typerow) -> output
    rnn_kernel<8><<<2048/8, 64, 0, stream>>>(
        x0, t0, pooled0,
        Wc, W_h, bb, W_x + 16384,
        out);
}

// Round 2
// 814.124 us; speedup vs baseline: 1.3055x; 1.3055x over previous
//
#include <hip/hip_runtime.h>
#include <hip/hip_bf16.h>

// Sizes (fixed): B=2048, C=16, L=3, D=128, H=128, ED=8, T=4
// N = [2048, 32768, 524288]
#define WX_STRIDE (132*128)   // 16896 floats per level in W_x

typedef __attribute__((ext_vector_type(8))) short bf16x8;
typedef __attribute__((ext_vector_type(4))) float f32x4;

__device__ __forceinline__ float tanh_fast(float x) {
    return 1.f - 2.f / (__expf(2.f * x) + 1.f);
}
__device__ __forceinline__ float sigmoid_fast(float x) {
    return 1.f / (1.f + __expf(-x));
}
__device__ __forceinline__ short f2bf_rne(float x) {
    unsigned u = __float_as_uint(x);
    u += 0x7fffu + ((u >> 16) & 1u);
    return (short)(u >> 16);
}
__device__ __forceinline__ float bf2f(short s) {
    return __uint_as_float(((unsigned)(unsigned short)s) << 16);
}

// ---------------------------------------------------------------------------
// prep: Wc[l] = W_fe @ W_x[l][:128,:], bb[l] = b_fe @ W_x[l][:128,:] + b_r[l]
// ---------------------------------------------------------------------------
__global__ __launch_bounds__(128)
void prep_kernel(const float* __restrict__ W_fe, const float* __restrict__ b_fe,
                 const float* __restrict__ W_x, const float* __restrict__ b_r,
                 float* __restrict__ Wc, float* __restrict__ bb)
{
    const int l = blockIdx.x;
    const int d = blockIdx.y;
    const int h = threadIdx.x;
    const float* wx = W_x + l * WX_STRIDE;
    if (d < 128) {
        const float* fer = W_fe + d * 128;
        float s = 0.f;
        for (int k = 0; k < 128; ++k) s = fmaf(fer[k], wx[k*128 + h], s);
        Wc[l*16384 + d*128 + h] = s;
    } else {
        float s = b_r[l*128 + h];
        for (int k = 0; k < 128; ++k) s = fmaf(b_fe[k], wx[k*128 + h], s);
        bb[l*128 + h] = s;
    }
}

// prep_t: bf16 n-major (transposed) copies of Wc2 and Wg1 for MFMA B-frags
__global__ __launch_bounds__(128)
void prep_t_kernel(const float* __restrict__ Wc2, const float* __restrict__ Wg1,
                   unsigned short* __restrict__ Wc2t, unsigned short* __restrict__ Wg1t)
{
    const int n = blockIdx.x;
    const int k = threadIdx.x;
    Wc2t[n*128 + k] = (unsigned short)f2bf_rne(Wc2[k*128 + n]);
    Wg1t[n*128 + k] = (unsigned short)f2bf_rne(Wg1[k*128 + n]);
}

// ---------------------------------------------------------------------------
// leafz: fused level-1 pipeline, one 16-leaf parent tile per wave iteration.
//   f  = tanh(x2_tile @ Wc2 + bb2 + typerow)        [MFMA, A split hi/lo]
//   Z  = f @ Wg1                                    [MFMA, A split hi/lo]
//   g  = sigmoid(E1 . We1);  P = A1 * g
//   pooled1 = max_c relu(P @ Z + bg1)               [fp32 VALU]
// Uses (A*g)@(h2@Wg) == ((A*g)@h2)@Wg associativity to avoid per-parent GEMM.
// LDS: Wc2t/Wg1t bf16 padded stride 136 (conflict-free b128 B-frag reads),
//      per-wave 16x132 fp32 buffer (x tile -> f -> Z), per-wave wmat.
// ---------------------------------------------------------------------------
#define LZ_WAVES 8
#define SM_WCT   0                       // 128*272 = 34816
#define SM_WGT   34816                   // +34816 = 69632
#define SM_WXT   69632                   // 4*132*4 = 2112 -> 71744
#define SM_XBUF  71744                   // + wave*8448 (16*132*4) -> 139328
#define SM_WMAT  139328                  // + wave*1024 -> 147520
#define SM_TOTAL 147520

__global__ __launch_bounds__(512, 2)
void leafz_kernel(const float* __restrict__ x2, const int* __restrict__ t2,
                  const float* __restrict__ A1, const float* __restrict__ E1,
                  const unsigned short* __restrict__ Wc2t,
                  const unsigned short* __restrict__ Wg1t,
                  const float* __restrict__ bb2,
                  const float* __restrict__ WxT2,   // W_x[2] rows 128..131
                  const float* __restrict__ We1,    // W_e[1]
                  const float* __restrict__ bg1,    // b_g[1]
                  float* __restrict__ pooled1)
{
    extern __shared__ char smem[];
    const int tid  = threadIdx.x;
    const int wave = tid >> 6;
    const int lane = tid & 63;
    const int l = lane & 15;
    const int q = lane >> 4;

    // stage weights into padded LDS (row stride 136 bf16 = 272 B)
    {
        const unsigned* g = (const unsigned*)Wc2t;
        for (int idx = tid; idx < 8192; idx += 512) {
            int n = idx >> 6, kp = idx & 63;
            *(unsigned*)(smem + SM_WCT + n*272 + kp*4) = g[idx];
        }
        g = (const unsigned*)Wg1t;
        for (int idx = tid; idx < 8192; idx += 512) {
            int n = idx >> 6, kp = idx & 63;
            *(unsigned*)(smem + SM_WGT + n*272 + kp*4) = g[idx];
        }
        {   // type rows, stride 132 floats
            int ty = tid >> 7, col = tid & 127;
            *(float*)(smem + SM_WXT + (ty*132 + col)*4) = WxT2[ty*128 + col];
        }
    }
    __syncthreads();

    float bias[8];
    #pragma unroll
    for (int nt = 0; nt < 8; ++nt) bias[nt] = bb2[nt*16 + l];
    const float bgl0 = bg1[2*lane], bgl1 = bg1[2*lane + 1];
    float we[8];
    #pragma unroll
    for (int j = 0; j < 8; ++j) we[j] = We1[j];

    float* xbuf = (float*)(smem + SM_XBUF + wave*8448);
    float* wmat = (float*)(smem + SM_WMAT + wave*1024);

    const int tile0 = (blockIdx.x * LZ_WAVES + wave) * 16;

    // prologue: tile 0 -> LDS
    float4 xf[8];
    {
        const float4* src = (const float4*)x2 + (size_t)tile0 * 512;
        #pragma unroll
        for (int w8 = 0; w8 < 8; ++w8) xf[w8] = src[w8*64 + lane];
        #pragma unroll
        for (int w8 = 0; w8 < 8; ++w8) {
            int idx = w8*64 + lane;
            *(float4*)(xbuf + (idx >> 5)*132 + (idx & 31)*4) = xf[w8];
        }
    }

    for (int it = 0; it < 16; ++it) {
        const int p = tile0 + it;
        // prefetch next x tile into regs
        if (it + 1 < 16) {
            const float4* src = (const float4*)x2 + (size_t)(p + 1) * 512;
            #pragma unroll
            for (int w8 = 0; w8 < 8; ++w8) xf[w8] = src[w8*64 + lane];
        }
        int tyr[4];
        #pragma unroll
        for (int r = 0; r < 4; ++r) tyr[r] = t2[p*16 + q*4 + r];

        // ---- GEMM1: acc = bias + typerow + x @ Wc2 ----
        f32x4 acc[8];
        #pragma unroll
        for (int nt = 0; nt < 8; ++nt) {
            #pragma unroll
            for (int r = 0; r < 4; ++r)
                acc[nt][r] = bias[nt] +
                    *(const float*)(smem + SM_WXT + (tyr[r]*132 + nt*16 + l)*4);
        }
        #pragma unroll
        for (int ks = 0; ks < 4; ++ks) {
            const float* ap = xbuf + l*132 + ks*32 + q*8;
            f32x4 a0 = *(const f32x4*)ap;
            f32x4 a1 = *(const f32x4*)(ap + 4);
            bf16x8 ahi, alo;
            #pragma unroll
            for (int j = 0; j < 4; ++j) {
                short h0 = f2bf_rne(a0[j]);
                ahi[j]   = h0; alo[j]   = f2bf_rne(a0[j] - bf2f(h0));
                short h1 = f2bf_rne(a1[j]);
                ahi[j+4] = h1; alo[j+4] = f2bf_rne(a1[j] - bf2f(h1));
            }
            #pragma unroll
            for (int nt = 0; nt < 8; ++nt) {
                bf16x8 b = *(const bf16x8*)(smem + SM_WCT + (nt*16 + l)*272 + ks*64 + q*16);
                acc[nt] = __builtin_amdgcn_mfma_f32_16x16x32_bf16(ahi, b, acc[nt], 0, 0, 0);
                acc[nt] = __builtin_amdgcn_mfma_f32_16x16x32_bf16(alo, b, acc[nt], 0, 0, 0);
            }
        }

        // issue E/A loads now; consumed after GEMM2
        float4 ef[8]; float4 av;
        {
            const float4* Ep = (const float4*)(E1 + (size_t)p * 2048);
            #pragma unroll
            for (int j = 0; j < 4; ++j) {
                ef[2*j]     = Ep[2*(4*lane + j)];
                ef[2*j + 1] = Ep[2*(4*lane + j) + 1];
            }
            av = ((const float4*)(A1 + (size_t)p * 256))[lane];
        }

        // tanh -> f into xbuf (C-frag layout: row q*4+r, col nt*16+l)
        #pragma unroll
        for (int nt = 0; nt < 8; ++nt) {
            #pragma unroll
            for (int r = 0; r < 4; ++r)
                xbuf[(q*4 + r)*132 + nt*16 + l] = tanh_fast(acc[nt][r]);
        }

        // ---- GEMM2: Z = f @ Wg1 ----
        f32x4 accz[8];
        #pragma unroll
        for (int nt = 0; nt < 8; ++nt) accz[nt] = (f32x4){0.f, 0.f, 0.f, 0.f};
        #pragma unroll
        for (int ks = 0; ks < 4; ++ks) {
            const float* ap = xbuf + l*132 + ks*32 + q*8;
            f32x4 a0 = *(const f32x4*)ap;
            f32x4 a1 = *(const f32x4*)(ap + 4);
            bf16x8 ahi, alo;
            #pragma unroll
            for (int j = 0; j < 4; ++j) {
                short h0 = f2bf_rne(a0[j]);
                ahi[j]   = h0; alo[j]   = f2bf_rne(a0[j] - bf2f(h0));
                short h1 = f2bf_rne(a1[j]);
                ahi[j+4] = h1; alo[j+4] = f2bf_rne(a1[j] - bf2f(h1));
            }
            #pragma unroll
            for (int nt = 0; nt < 8; ++nt) {
                bf16x8 b = *(const bf16x8*)(smem + SM_WGT + (nt*16 + l)*272 + ks*64 + q*16);
                accz[nt] = __builtin_amdgcn_mfma_f32_16x16x32_bf16(ahi, b, accz[nt], 0, 0, 0);
                accz[nt] = __builtin_amdgcn_mfma_f32_16x16x32_bf16(alo, b, accz[nt], 0, 0, 0);
            }
        }

        // gating: wmat[4*lane+j] = A * sigmoid(E . We)
        #pragma unroll
        for (int j = 0; j < 4; ++j) {
            float4 e0 = ef[2*j], e1 = ef[2*j + 1];
            float z = e0.x*we[0] + e0.y*we[1] + e0.z*we[2] + e0.w*we[3]
                    + e1.x*we[4] + e1.y*we[5] + e1.z*we[6] + e1.w*we[7];
            float a = (j == 0) ? av.x : (j == 1) ? av.y : (j == 2) ? av.z : av.w;
            wmat[4*lane + j] = a * sigmoid_fast(z);
        }

        // Z -> xbuf (overwrite f; same-wave lgkmcnt ordering)
        #pragma unroll
        for (int nt = 0; nt < 8; ++nt) {
            #pragma unroll
            for (int r = 0; r < 4; ++r)
                xbuf[(q*4 + r)*132 + nt*16 + l] = accz[nt][r];
        }

        // read Z columns (2*lane, 2*lane+1) across 16 children
        float chx[16], chy[16];
        #pragma unroll
        for (int k = 0; k < 16; ++k) {
            float2 v = *(const float2*)(xbuf + k*132 + 2*lane);
            chx[k] = v.x; chy[k] = v.y;
        }

        // pooled = max_c relu(bg + sum_k wmat[c,k] * Z[k,:])
        float px = 0.f, py = 0.f;
        #pragma unroll
        for (int c = 0; c < 16; ++c) {
            float vx = bgl0, vy = bgl1;
            #pragma unroll
            for (int k4 = 0; k4 < 4; ++k4) {
                float4 w = *(const float4*)(wmat + c*16 + 4*k4);
                vx = fmaf(w.x, chx[4*k4+0], vx); vy = fmaf(w.x, chy[4*k4+0], vy);
                vx = fmaf(w.y, chx[4*k4+1], vx); vy = fmaf(w.y, chy[4*k4+1], vy);
                vx = fmaf(w.z, chx[4*k4+2], vx); vy = fmaf(w.z, chy[4*k4+2], vy);
                vx = fmaf(w.w, chx[4*k4+3], vx); vy = fmaf(w.w, chy[4*k4+3], vy);
            }
            px = fmaxf(px, vx); py = fmaxf(py, vy);
        }
        *(float2*)(pooled1 + (size_t)p*128 + 2*lane) = make_float2(px, py);

        // commit prefetched x tile to LDS for next iteration
        if (it + 1 < 16) {
            #pragma unroll
            for (int w8 = 0; w8 < 8; ++w8) {
                int idx = w8*64 + lane;
                *(float4*)(xbuf + (idx >> 5)*132 + (idx & 31)*4) = xf[w8];
            }
        }
    }
}

// ---------------------------------------------------------------------------
// gnn_kernel<false>: level-0 GNN (h1 children from global), fp32 VALU
// ---------------------------------------------------------------------------
template<bool COMPUTE_CH>
__global__ __launch_bounds__(64)
void gnn_kernel(const float* __restrict__ xc,
                const int*   __restrict__ tc,
                const float* __restrict__ A,
                const float* __restrict__ E,
                const float* __restrict__ We,
                const float* __restrict__ Wg,
                const float* __restrict__ bg,
                const float* __restrict__ Wcl,
                const float* __restrict__ bbl,
                const float* __restrict__ WxT,
                float* __restrict__ pooled)
{
    __shared__ __align__(16) float buf[16*128];
    __shared__ __align__(16) float wmat[256];
    const int p = blockIdx.x;
    const int t = threadIdx.x;
    const int c0 = 2*t, c1 = 2*t + 1;

    float2 ch[16];
    #pragma unroll
    for (int c = 0; c < 16; ++c) {
        const float2* hp = (const float2*)(xc + ((size_t)p*16 + c) * 128);
        ch[c] = hp[t];
    }

    {
        const float4* Ep = (const float4*)(E + (size_t)p * 2048);
        const float*  Ap = A + (size_t)p * 256;
        const float we0=We[0], we1=We[1], we2=We[2], we3=We[3];
        const float we4=We[4], we5=We[5], we6=We[6], we7=We[7];
        #pragma unroll
        for (int j = 0; j < 4; ++j) {
            const int qe = 4*t + j;
            const float4 e0 = Ep[2*qe];
            const float4 e1 = Ep[2*qe + 1];
            float z = e0.x*we0 + e0.y*we1 + e0.z*we2 + e0.w*we3
                    + e1.x*we4 + e1.y*we5 + e1.z*we6 + e1.w*we7;
            wmat[qe] = Ap[qe] * sigmoid_fast(z);
        }
    }
    __syncthreads();

    float2 m[16];
    const float4* wm4 = (const float4*)wmat;
    #pragma unroll
    for (int c = 0; c < 16; ++c) {
        float mx = 0.f, my = 0.f;
        #pragma unroll
        for (int k4 = 0; k4 < 4; ++k4) {
            const float4 w = wm4[c*4 + k4];
            mx = fmaf(w.x, ch[4*k4+0].x, mx); my = fmaf(w.x, ch[4*k4+0].y, my);
            mx = fmaf(w.y, ch[4*k4+1].x, mx); my = fmaf(w.y, ch[4*k4+1].y, my);
            mx = fmaf(w.z, ch[4*k4+2].x, mx); my = fmaf(w.z, ch[4*k4+2].y, my);
            mx = fmaf(w.w, ch[4*k4+3].x, mx); my = fmaf(w.w, ch[4*k4+3].y, my);
        }
        m[c].x = mx; m[c].y = my;
    }
    #pragma unroll
    for (int c = 0; c < 16; ++c) ((float2*)buf)[c*64 + t] = m[c];
    __syncthreads();

    float2 acc[16];
    #pragma unroll
    for (int c = 0; c < 16; ++c) { acc[c].x = bg[c0]; acc[c].y = bg[c1]; }
    const float2* Wg2 = (const float2*)Wg;
    for (int d0 = 0; d0 < 128; d0 += 4) {
        const float2 w0 = Wg2[(d0+0)*64 + t];
        const float2 w1 = Wg2[(d0+1)*64 + t];
        const float2 w2 = Wg2[(d0+2)*64 + t];
        const float2 w3 = Wg2[(d0+3)*64 + t];
        const float4* mv4 = (const float4*)buf + (d0 >> 2);
        #pragma unroll
        for (int c = 0; c < 16; ++c) {
            const float4 mv = mv4[c*32];
            acc[c].x = fmaf(mv.x, w0.x, acc[c].x);
            acc[c].y = fmaf(mv.x, w0.y, acc[c].y);
            acc[c].x = fmaf(mv.y, w1.x, acc[c].x);
            acc[c].y = fmaf(mv.y, w1.y, acc[c].y);
            acc[c].x = fmaf(mv.z, w2.x, acc[c].x);
            acc[c].y = fmaf(mv.z, w2.y, acc[c].y);
            acc[c].x = fmaf(mv.w, w3.x, acc[c].x);
            acc[c].y = fmaf(mv.w, w3.y, acc[c].y);
        }
    }
    float px = acc[0].x, py = acc[0].y;
    #pragma unroll
    for (int c = 1; c < 16; ++c) { px = fmaxf(px, acc[c].x); py = fmaxf(py, acc[c].y); }
    px = fmaxf(px, 0.f); py = fmaxf(py, 0.f);
    ((float2*)pooled)[(size_t)p*64 + t] = make_float2(px, py);
}

// ---------------------------------------------------------------------------
// rnn_kernel: out[r] = tanh(x[r] @ Wc[l] + pool[r] @ W_h[l] + bb[l] + typerow)
// ---------------------------------------------------------------------------
template<int R>
__global__ __launch_bounds__(64)
void rnn_kernel(const float* __restrict__ x, const int* __restrict__ tt,
                const float* __restrict__ pool,
                const float* __restrict__ Wcl, const float* __restrict__ Whl,
                const float* __restrict__ bbl, const float* __restrict__ WxT,
                float* __restrict__ out)
{
    __shared__ __align__(16) float xs[R*128];
    __shared__ __align__(16) float ps[R*128];
    const int t = threadIdx.x;
    const int row0 = blockIdx.x * R;

    const float4* xg4 = (const float4*)(x + (size_t)row0 * 128);
    const float4* pg4 = (const float4*)(pool + (size_t)row0 * 128);
    float4* xs4w = (float4*)xs;
    float4* ps4w = (float4*)ps;
    #pragma unroll
    for (int i = t; i < R*32; i += 64) { xs4w[i] = xg4[i]; ps4w[i] = pg4[i]; }
    __syncthreads();

    const int c0 = 2*t, c1 = c0 + 1;
    float2 acc[R];
    #pragma unroll
    for (int r = 0; r < R; ++r) {
        const int ty = tt[row0 + r];
        const float* trw = WxT + ty*128;
        acc[r].x = bbl[c0] + trw[c0];
        acc[r].y = bbl[c1] + trw[c1];
    }
    const float2* W2 = (const float2*)Wcl;
    for (int d0 = 0; d0 < 128; d0 += 4) {
        const float2 w0 = W2[(d0+0)*64 + t];
        const float2 w1 = W2[(d0+1)*64 + t];
        const float2 w2 = W2[(d0+2)*64 + t];
        const float2 w3 = W2[(d0+3)*64 + t];
        const float4* xv4 = (const float4*)xs + (d0 >> 2);
        #pragma unroll
        for (int r = 0; r < R; ++r) {
            const float4 xv = xv4[r*32];
            acc[r].x = fmaf(xv.x, w0.x, acc[r].x);
            acc[r].y = fmaf(xv.x, w0.y, acc[r].y);
            acc[r].x = fmaf(xv.y, w1.x, acc[r].x);
            acc[r].y = fmaf(xv.y, w1.y, acc[r].y);
            acc[r].x = fmaf(xv.z, w2.x, acc[r].x);
            acc[r].y = fmaf(xv.z, w2.y, acc[r].y);
            acc[r].x = fmaf(xv.w, w3.x, acc[r].x);
            acc[r].y = fmaf(xv.w, w3.y, acc[r].y);
        }
    }
    const float2* Wh2 = (const float2*)Whl;
    for (int d0 = 0; d0 < 128; d0 += 4) {
        const float2 w0 = Wh2[(d0+0)*64 + t];
        const float2 w1 = Wh2[(d0+1)*64 + t];
        const float2 w2 = Wh2[(d0+2)*64 + t];
        const float2 w3 = Wh2[(d0+3)*64 + t];
        const float4* pv4 = (const float4*)ps + (d0 >> 2);
        #pragma unroll
        for (int r = 0; r < R; ++r) {
            const float4 pv = pv4[r*32];
            acc[r].x = fmaf(pv.x, w0.x, acc[r].x);
            acc[r].y = fmaf(pv.x, w0.y, acc[r].y);
            acc[r].x = fmaf(pv.y, w1.x, acc[r].x);
            acc[r].y = fmaf(pv.y, w1.y, acc[r].y);
            acc[r].x = fmaf(pv.z, w2.x, acc[r].x);
            acc[r].y = fmaf(pv.z, w2.y, acc[r].y);
            acc[r].x = fmaf(pv.w, w3.x, acc[r].x);
            acc[r].y = fmaf(pv.w, w3.y, acc[r].y);
        }
    }
    #pragma unroll
    for (int r = 0; r < R; ++r) {
        ((float2*)out)[(size_t)(row0 + r)*64 + t] =
            make_float2(tanh_fast(acc[r].x), tanh_fast(acc[r].y));
    }
}

// ---------------------------------------------------------------------------
extern "C" void kernel_launch(void* const* d_in, const int* in_sizes, int n_in,
                              void* d_out, int out_size, void* d_ws, size_t ws_size,
                              hipStream_t stream) {
    const float* x0   = (const float*)d_in[0];
    const float* x1   = (const float*)d_in[1];
    const float* x2   = (const float*)d_in[2];
    const int*   t0   = (const int*)d_in[3];
    const int*   t1   = (const int*)d_in[4];
    const int*   t2   = (const int*)d_in[5];
    const float* A0   = (const float*)d_in[6];
    const float* A1   = (const float*)d_in[7];
    const float* E0   = (const float*)d_in[8];
    const float* E1   = (const float*)d_in[9];
    const float* W_fe = (const float*)d_in[10];
    const float* b_fe = (const float*)d_in[11];
    const float* W_x  = (const float*)d_in[12];
    const float* W_h  = (const float*)d_in[13];
    const float* W_e  = (const float*)d_in[14];
    const float* W_g  = (const float*)d_in[15];
    const float* b_g  = (const float*)d_in[16];
    const float* b_r  = (const float*)d_in[17];
    float* out = (float*)d_out;

    // ws layout (floats): Wc[49152] | bb[384] | pooled1[4194304] | h1[4194304]
    //                     | pooled0[262144] | Wc2t(bf16 as 8192 f) | Wg1t(8192 f)
    float* ws      = (float*)d_ws;
    float* Wc      = ws;
    float* bb      = ws + 49152;
    float* pooled1 = ws + 49536;
    float* h1v     = pooled1 + 4194304;
    float* pooled0 = h1v + 4194304;
    unsigned short* Wc2t = (unsigned short*)(pooled0 + 262144);
    unsigned short* Wg1t = Wc2t + 16384;

    prep_kernel<<<dim3(3, 129), 128, 0, stream>>>(W_fe, b_fe, W_x, b_r, Wc, bb);
    prep_t_kernel<<<128, 128, 0, stream>>>(Wc + 2*16384, W_g + 16384, Wc2t, Wg1t);

    // fused level-2 + level-1 GNN (MFMA): x2 -> pooled1, no h2/Z round-trip
    static int lds_attr_set_ok = 0;  // value unused; call every time (idempotent)
    (void)lds_attr_set_ok;
    hipFuncSetAttribute((const void*)leafz_kernel,
                        hipFuncAttributeMaxDynamicSharedMemorySize, SM_TOTAL);
    leafz_kernel<<<256, 512, SM_TOTAL, stream>>>(
        x2, t2, A1, E1, Wc2t, Wg1t,
        bb + 256, W_x + 2*WX_STRIDE + 16384, W_e + 8, b_g + 128,
        pooled1);

    rnn_kernel<8><<<32768/8, 64, 0, stream>>>(
        x1, t1, pooled1,
        Wc + 16384, W_h + 16384, bb + 128, W_x + WX_STRIDE + 16384,
        h1v);

    gnn_kernel<false><<<2048, 64, 0, stream>>>(
        h1v, nullptr, A0, E0,
        W_e, W_g, b_g,
        nullptr, nullptr, nullptr,
        pooled0);

    rnn_kernel<8><<<2048/8, 64, 0, stream>>>(
        x0, t0, pooled0,
        Wc, W_h, bb, W_x + 16384,
        out);
}

// Round 3
// 753.678 us; speedup vs baseline: 1.4102x; 1.0802x over previous
//
#include <hip/hip_runtime.h>
#include <hip/hip_bf16.h>

// Sizes (fixed): B=2048, C=16, L=3, D=128, H=128, ED=8, T=4
// N = [2048, 32768, 524288]
#define WX_STRIDE (132*128)   // 16896 floats per level in W_x

typedef __attribute__((ext_vector_type(8))) short bf16x8;
typedef __attribute__((ext_vector_type(4))) float f32x4;

__device__ __forceinline__ float tanh_fast(float x) {
    return 1.f - 2.f / (__expf(2.f * x) + 1.f);
}
__device__ __forceinline__ float sigmoid_fast(float x) {
    return 1.f / (1.f + __expf(-x));
}
__device__ __forceinline__ short f2bf_rne(float x) {
    unsigned u = __float_as_uint(x);
    u += 0x7fffu + ((u >> 16) & 1u);
    return (short)(u >> 16);
}
__device__ __forceinline__ float bf2f(short s) {
    return __uint_as_float(((unsigned)(unsigned short)s) << 16);
}

// ---------------------------------------------------------------------------
// prep: Wc[l] = W_fe @ W_x[l][:128,:], bb[l] = b_fe @ W_x[l][:128,:] + b_r[l]
// ---------------------------------------------------------------------------
__global__ __launch_bounds__(128)
void prep_kernel(const float* __restrict__ W_fe, const float* __restrict__ b_fe,
                 const float* __restrict__ W_x, const float* __restrict__ b_r,
                 float* __restrict__ Wc, float* __restrict__ bb)
{
    const int l = blockIdx.x;
    const int d = blockIdx.y;
    const int h = threadIdx.x;
    const float* wx = W_x + l * WX_STRIDE;
    if (d < 128) {
        const float* fer = W_fe + d * 128;
        float s = 0.f;
        for (int k = 0; k < 128; ++k) s = fmaf(fer[k], wx[k*128 + h], s);
        Wc[l*16384 + d*128 + h] = s;
    } else {
        float s = b_r[l*128 + h];
        for (int k = 0; k < 128; ++k) s = fmaf(b_fe[k], wx[k*128 + h], s);
        bb[l*128 + h] = s;
    }
}

// prep_t: bf16 n-major (transposed) copies of Wc2 and Wg1 for MFMA B-frags
__global__ __launch_bounds__(128)
void prep_t_kernel(const float* __restrict__ Wc2, const float* __restrict__ Wg1,
                   unsigned short* __restrict__ Wc2t, unsigned short* __restrict__ Wg1t)
{
    const int n = blockIdx.x;
    const int k = threadIdx.x;
    Wc2t[n*128 + k] = (unsigned short)f2bf_rne(Wc2[k*128 + n]);
    Wg1t[n*128 + k] = (unsigned short)f2bf_rne(Wg1[k*128 + n]);
}

// ---------------------------------------------------------------------------
// leafz: fused level-1 pipeline, one 16-leaf parent per wave iteration.
//   gate -> wmat (LDS)                              [fp32 VALU, E consumed hot]
//   f  = tanh(x2_tile @ Wc2 + bb2 + typerow)        [MFMA, A direct from global,
//                                                    split hi/lo bf16]
//   Z  = f @ Wg1                                    [MFMA via LDS round-trip]
//   pooled1 = max_c relu((A*g) @ Z + bg1)           [fp32 VALU]
// R2 lesson: no float4[8] array may live across an MFMA section (spills 268 MB).
// A-frags for GEMM1 load straight from global: lane(l,q) reads row l cols
// ks*32+q*8 -> each 128B line consumed by exactly 4 lanes in one dwordx4.
// ---------------------------------------------------------------------------
#define LZ_WAVES 8
#define SM_WCT   0                       // 128*272 = 34816
#define SM_WGT   34816                   // +34816 = 69632
#define SM_WXT   69632                   // 4*132*4 = 2112 -> 71744
#define SM_XBUF  71744                   // + wave*8448 (16*132*4) -> 139328
#define SM_WMAT  139328                  // + wave*1024 -> 147520
#define SM_TOTAL 147520

__global__ __launch_bounds__(512, 2)
void leafz_kernel(const float* __restrict__ x2, const int* __restrict__ t2,
                  const float* __restrict__ A1, const float* __restrict__ E1,
                  const unsigned short* __restrict__ Wc2t,
                  const unsigned short* __restrict__ Wg1t,
                  const float* __restrict__ bb2,
                  const float* __restrict__ WxT2,   // W_x[2] rows 128..131
                  const float* __restrict__ We1,    // W_e[1]
                  const float* __restrict__ bg1,    // b_g[1]
                  float* __restrict__ pooled1)
{
    extern __shared__ char smem[];
    const int tid  = threadIdx.x;
    const int wave = tid >> 6;
    const int lane = tid & 63;
    const int l = lane & 15;
    const int q = lane >> 4;

    // stage weights into padded LDS (row stride 136 bf16 = 272 B)
    {
        const unsigned* g = (const unsigned*)Wc2t;
        for (int idx = tid; idx < 8192; idx += 512) {
            int n = idx >> 6, kp = idx & 63;
            *(unsigned*)(smem + SM_WCT + n*272 + kp*4) = g[idx];
        }
        g = (const unsigned*)Wg1t;
        for (int idx = tid; idx < 8192; idx += 512) {
            int n = idx >> 6, kp = idx & 63;
            *(unsigned*)(smem + SM_WGT + n*272 + kp*4) = g[idx];
        }
        {   // type rows, stride 132 floats
            int ty = tid >> 7, col = tid & 127;
            *(float*)(smem + SM_WXT + (ty*132 + col)*4) = WxT2[ty*128 + col];
        }
    }
    __syncthreads();

    float bias[8];
    #pragma unroll
    for (int nt = 0; nt < 8; ++nt) bias[nt] = bb2[nt*16 + l];
    const float bgl0 = bg1[2*lane], bgl1 = bg1[2*lane + 1];
    float we[8];
    #pragma unroll
    for (int j = 0; j < 8; ++j) we[j] = We1[j];

    float* xbuf = (float*)(smem + SM_XBUF + wave*8448);
    float* wmat = (float*)(smem + SM_WMAT + wave*1024);

    const int tile0 = (blockIdx.x * LZ_WAVES + wave) * 16;

    for (int it = 0; it < 16; ++it) {
        const int p = tile0 + it;

        // ---- issue GEMM1 A-operand loads (direct from global, coalesced
        //      at cache-line granularity: 4 lanes per 128B line) ----
        const float* xrow = x2 + (size_t)p*2048 + l*128 + q*8;
        f32x4 xa[8];
        #pragma unroll
        for (int ks = 0; ks < 4; ++ks) {
            xa[2*ks]     = *(const f32x4*)(xrow + ks*32);
            xa[2*ks + 1] = *(const f32x4*)(xrow + ks*32 + 4);
        }

        // ---- E/A loads, consumed immediately into the gate (no long-lived
        //      register arrays across MFMA sections!) ----
        {
            const float4* Ep = (const float4*)(E1 + (size_t)p * 2048);
            const float4  av = ((const float4*)(A1 + (size_t)p * 256))[lane];
            #pragma unroll
            for (int j = 0; j < 4; ++j) {
                const float4 e0 = Ep[2*(4*lane + j)];
                const float4 e1 = Ep[2*(4*lane + j) + 1];
                float z = e0.x*we[0] + e0.y*we[1] + e0.z*we[2] + e0.w*we[3]
                        + e1.x*we[4] + e1.y*we[5] + e1.z*we[6] + e1.w*we[7];
                float a = (j == 0) ? av.x : (j == 1) ? av.y : (j == 2) ? av.z : av.w;
                wmat[4*lane + j] = a * sigmoid_fast(z);
            }
        }

        int tyr[4];
        #pragma unroll
        for (int r = 0; r < 4; ++r) tyr[r] = t2[p*16 + q*4 + r];

        // ---- GEMM1: acc = bias + typerow + x @ Wc2 ----
        f32x4 acc[8];
        #pragma unroll
        for (int nt = 0; nt < 8; ++nt) {
            #pragma unroll
            for (int r = 0; r < 4; ++r)
                acc[nt][r] = bias[nt] +
                    *(const float*)(smem + SM_WXT + (tyr[r]*132 + nt*16 + l)*4);
        }
        #pragma unroll
        for (int ks = 0; ks < 4; ++ks) {
            const f32x4 a0 = xa[2*ks];
            const f32x4 a1 = xa[2*ks + 1];
            bf16x8 ahi, alo;
            #pragma unroll
            for (int j = 0; j < 4; ++j) {
                short h0 = f2bf_rne(a0[j]);
                ahi[j]   = h0; alo[j]   = f2bf_rne(a0[j] - bf2f(h0));
                short h1 = f2bf_rne(a1[j]);
                ahi[j+4] = h1; alo[j+4] = f2bf_rne(a1[j] - bf2f(h1));
            }
            #pragma unroll
            for (int nt = 0; nt < 8; ++nt) {
                bf16x8 b = *(const bf16x8*)(smem + SM_WCT + (nt*16 + l)*272 + ks*64 + q*16);
                acc[nt] = __builtin_amdgcn_mfma_f32_16x16x32_bf16(ahi, b, acc[nt], 0, 0, 0);
                acc[nt] = __builtin_amdgcn_mfma_f32_16x16x32_bf16(alo, b, acc[nt], 0, 0, 0);
            }
        }

        // tanh -> f into xbuf (C-frag layout: row q*4+r, col nt*16+l)
        #pragma unroll
        for (int nt = 0; nt < 8; ++nt) {
            #pragma unroll
            for (int r = 0; r < 4; ++r)
                xbuf[(q*4 + r)*132 + nt*16 + l] = tanh_fast(acc[nt][r]);
        }

        // ---- GEMM2: Z = f @ Wg1 ----
        f32x4 accz[8];
        #pragma unroll
        for (int nt = 0; nt < 8; ++nt) accz[nt] = (f32x4){0.f, 0.f, 0.f, 0.f};
        #pragma unroll
        for (int ks = 0; ks < 4; ++ks) {
            const float* ap = xbuf + l*132 + ks*32 + q*8;
            f32x4 a0 = *(const f32x4*)ap;
            f32x4 a1 = *(const f32x4*)(ap + 4);
            bf16x8 ahi, alo;
            #pragma unroll
            for (int j = 0; j < 4; ++j) {
                short h0 = f2bf_rne(a0[j]);
                ahi[j]   = h0; alo[j]   = f2bf_rne(a0[j] - bf2f(h0));
                short h1 = f2bf_rne(a1[j]);
                ahi[j+4] = h1; alo[j+4] = f2bf_rne(a1[j] - bf2f(h1));
            }
            #pragma unroll
            for (int nt = 0; nt < 8; ++nt) {
                bf16x8 b = *(const bf16x8*)(smem + SM_WGT + (nt*16 + l)*272 + ks*64 + q*16);
                accz[nt] = __builtin_amdgcn_mfma_f32_16x16x32_bf16(ahi, b, accz[nt], 0, 0, 0);
                accz[nt] = __builtin_amdgcn_mfma_f32_16x16x32_bf16(alo, b, accz[nt], 0, 0, 0);
            }
        }

        // Z -> xbuf (overwrite f; same-wave lgkmcnt ordering)
        #pragma unroll
        for (int nt = 0; nt < 8; ++nt) {
            #pragma unroll
            for (int r = 0; r < 4; ++r)
                xbuf[(q*4 + r)*132 + nt*16 + l] = accz[nt][r];
        }

        // read Z columns (2*lane, 2*lane+1) across 16 children
        float chx[16], chy[16];
        #pragma unroll
        for (int k = 0; k < 16; ++k) {
            float2 v = *(const float2*)(xbuf + k*132 + 2*lane);
            chx[k] = v.x; chy[k] = v.y;
        }

        // pooled = max_c relu(bg + sum_k wmat[c,k] * Z[k,:])
        // wmat reads are wave-uniform -> LDS broadcast, conflict-free
        float px = 0.f, py = 0.f;
        #pragma unroll
        for (int c = 0; c < 16; ++c) {
            float vx = bgl0, vy = bgl1;
            #pragma unroll
            for (int k4 = 0; k4 < 4; ++k4) {
                float4 w = *(const float4*)(wmat + c*16 + 4*k4);
                vx = fmaf(w.x, chx[4*k4+0], vx); vy = fmaf(w.x, chy[4*k4+0], vy);
                vx = fmaf(w.y, chx[4*k4+1], vx); vy = fmaf(w.y, chy[4*k4+1], vy);
                vx = fmaf(w.z, chx[4*k4+2], vx); vy = fmaf(w.z, chy[4*k4+2], vy);
                vx = fmaf(w.w, chx[4*k4+3], vx); vy = fmaf(w.w, chy[4*k4+3], vy);
            }
            px = fmaxf(px, vx); py = fmaxf(py, vy);
        }
        *(float2*)(pooled1 + (size_t)p*128 + 2*lane) = make_float2(px, py);
    }
}

// ---------------------------------------------------------------------------
// gnn_kernel<false>: level-0 GNN (h1 children from global), fp32 VALU
// ---------------------------------------------------------------------------
template<bool COMPUTE_CH>
__global__ __launch_bounds__(64)
void gnn_kernel(const float* __restrict__ xc,
                const int*   __restrict__ tc,
                const float* __restrict__ A,
                const float* __restrict__ E,
                const float* __restrict__ We,
                const float* __restrict__ Wg,
                const float* __restrict__ bg,
                const float* __restrict__ Wcl,
                const float* __restrict__ bbl,
                const float* __restrict__ WxT,
                float* __restrict__ pooled)
{
    __shared__ __align__(16) float buf[16*128];
    __shared__ __align__(16) float wmat[256];
    const int p = blockIdx.x;
    const int t = threadIdx.x;
    const int c0 = 2*t, c1 = 2*t + 1;

    float2 ch[16];
    #pragma unroll
    for (int c = 0; c < 16; ++c) {
        const float2* hp = (const float2*)(xc + ((size_t)p*16 + c) * 128);
        ch[c] = hp[t];
    }

    {
        const float4* Ep = (const float4*)(E + (size_t)p * 2048);
        const float*  Ap = A + (size_t)p * 256;
        const float we0=We[0], we1=We[1], we2=We[2], we3=We[3];
        const float we4=We[4], we5=We[5], we6=We[6], we7=We[7];
        #pragma unroll
        for (int j = 0; j < 4; ++j) {
            const int qe = 4*t + j;
            const float4 e0 = Ep[2*qe];
            const float4 e1 = Ep[2*qe + 1];
            float z = e0.x*we0 + e0.y*we1 + e0.z*we2 + e0.w*we3
                    + e1.x*we4 + e1.y*we5 + e1.z*we6 + e1.w*we7;
            wmat[qe] = Ap[qe] * sigmoid_fast(z);
        }
    }
    __syncthreads();

    float2 m[16];
    const float4* wm4 = (const float4*)wmat;
    #pragma unroll
    for (int c = 0; c < 16; ++c) {
        float mx = 0.f, my = 0.f;
        #pragma unroll
        for (int k4 = 0; k4 < 4; ++k4) {
            const float4 w = wm4[c*4 + k4];
            mx = fmaf(w.x, ch[4*k4+0].x, mx); my = fmaf(w.x, ch[4*k4+0].y, my);
            mx = fmaf(w.y, ch[4*k4+1].x, mx); my = fmaf(w.y, ch[4*k4+1].y, my);
            mx = fmaf(w.z, ch[4*k4+2].x, mx); my = fmaf(w.z, ch[4*k4+2].y, my);
            mx = fmaf(w.w, ch[4*k4+3].x, mx); my = fmaf(w.w, ch[4*k4+3].y, my);
        }
        m[c].x = mx; m[c].y = my;
    }
    #pragma unroll
    for (int c = 0; c < 16; ++c) ((float2*)buf)[c*64 + t] = m[c];
    __syncthreads();

    float2 acc[16];
    #pragma unroll
    for (int c = 0; c < 16; ++c) { acc[c].x = bg[c0]; acc[c].y = bg[c1]; }
    const float2* Wg2 = (const float2*)Wg;
    for (int d0 = 0; d0 < 128; d0 += 4) {
        const float2 w0 = Wg2[(d0+0)*64 + t];
        const float2 w1 = Wg2[(d0+1)*64 + t];
        const float2 w2 = Wg2[(d0+2)*64 + t];
        const float2 w3 = Wg2[(d0+3)*64 + t];
        const float4* mv4 = (const float4*)buf + (d0 >> 2);
        #pragma unroll
        for (int c = 0; c < 16; ++c) {
            const float4 mv = mv4[c*32];
            acc[c].x = fmaf(mv.x, w0.x, acc[c].x);
            acc[c].y = fmaf(mv.x, w0.y, acc[c].y);
            acc[c].x = fmaf(mv.y, w1.x, acc[c].x);
            acc[c].y = fmaf(mv.y, w1.y, acc[c].y);
            acc[c].x = fmaf(mv.z, w2.x, acc[c].x);
            acc[c].y = fmaf(mv.z, w2.y, acc[c].y);
            acc[c].x = fmaf(mv.w, w3.x, acc[c].x);
            acc[c].y = fmaf(mv.w, w3.y, acc[c].y);
        }
    }
    float px = acc[0].x, py = acc[0].y;
    #pragma unroll
    for (int c = 1; c < 16; ++c) { px = fmaxf(px, acc[c].x); py = fmaxf(py, acc[c].y); }
    px = fmaxf(px, 0.f); py = fmaxf(py, 0.f);
    ((float2*)pooled)[(size_t)p*64 + t] = make_float2(px, py);
}

// ---------------------------------------------------------------------------
// rnn_kernel: out[r] = tanh(x[r] @ Wc[l] + pool[r] @ W_h[l] + bb[l] + typerow)
// ---------------------------------------------------------------------------
template<int R>
__global__ __launch_bounds__(64)
void rnn_kernel(const float* __restrict__ x, const int* __restrict__ tt,
                const float* __restrict__ pool,
                const float* __restrict__ Wcl, const float* __restrict__ Whl,
                const float* __restrict__ bbl, const float* __restrict__ WxT,
                float* __restrict__ out)
{
    __shared__ __align__(16) float xs[R*128];
    __shared__ __align__(16) float ps[R*128];
    const int t = threadIdx.x;
    const int row0 = blockIdx.x * R;

    const float4* xg4 = (const float4*)(x + (size_t)row0 * 128);
    const float4* pg4 = (const float4*)(pool + (size_t)row0 * 128);
    float4* xs4w = (float4*)xs;
    float4* ps4w = (float4*)ps;
    #pragma unroll
    for (int i = t; i < R*32; i += 64) { xs4w[i] = xg4[i]; ps4w[i] = pg4[i]; }
    __syncthreads();

    const int c0 = 2*t, c1 = c0 + 1;
    float2 acc[R];
    #pragma unroll
    for (int r = 0; r < R; ++r) {
        const int ty = tt[row0 + r];
        const float* trw = WxT + ty*128;
        acc[r].x = bbl[c0] + trw[c0];
        acc[r].y = bbl[c1] + trw[c1];
    }
    const float2* W2 = (const float2*)Wcl;
    for (int d0 = 0; d0 < 128; d0 += 4) {
        const float2 w0 = W2[(d0+0)*64 + t];
        const float2 w1 = W2[(d0+1)*64 + t];
        const float2 w2 = W2[(d0+2)*64 + t];
        const float2 w3 = W2[(d0+3)*64 + t];
        const float4* xv4 = (const float4*)xs + (d0 >> 2);
        #pragma unroll
        for (int r = 0; r < R; ++r) {
            const float4 xv = xv4[r*32];
            acc[r].x = fmaf(xv.x, w0.x, acc[r].x);
            acc[r].y = fmaf(xv.x, w0.y, acc[r].y);
            acc[r].x = fmaf(xv.y, w1.x, acc[r].x);
            acc[r].y = fmaf(xv.y, w1.y, acc[r].y);
            acc[r].x = fmaf(xv.z, w2.x, acc[r].x);
            acc[r].y = fmaf(xv.z, w2.y, acc[r].y);
            acc[r].x = fmaf(xv.w, w3.x, acc[r].x);
            acc[r].y = fmaf(xv.w, w3.y, acc[r].y);
        }
    }
    const float2* Wh2 = (const float2*)Whl;
    for (int d0 = 0; d0 < 128; d0 += 4) {
        const float2 w0 = Wh2[(d0+0)*64 + t];
        const float2 w1 = Wh2[(d0+1)*64 + t];
        const float2 w2 = Wh2[(d0+2)*64 + t];
        const float2 w3 = Wh2[(d0+3)*64 + t];
        const float4* pv4 = (const float4*)ps + (d0 >> 2);
        #pragma unroll
        for (int r = 0; r < R; ++r) {
            const float4 pv = pv4[r*32];
            acc[r].x = fmaf(pv.x, w0.x, acc[r].x);
            acc[r].y = fmaf(pv.x, w0.y, acc[r].y);
            acc[r].x = fmaf(pv.y, w1.x, acc[r].x);
            acc[r].y = fmaf(pv.y, w1.y, acc[r].y);
            acc[r].x = fmaf(pv.z, w2.x, acc[r].x);
            acc[r].y = fmaf(pv.z, w2.y, acc[r].y);
            acc[r].x = fmaf(pv.w, w3.x, acc[r].x);
            acc[r].y = fmaf(pv.w, w3.y, acc[r].y);
        }
    }
    #pragma unroll
    for (int r = 0; r < R; ++r) {
        ((float2*)out)[(size_t)(row0 + r)*64 + t] =
            make_float2(tanh_fast(acc[r].x), tanh_fast(acc[r].y));
    }
}

// ---------------------------------------------------------------------------
extern "C" void kernel_launch(void* const* d_in, const int* in_sizes, int n_in,
                              void* d_out, int out_size, void* d_ws, size_t ws_size,
                              hipStream_t stream) {
    const float* x0   = (const float*)d_in[0];
    const float* x1   = (const float*)d_in[1];
    const float* x2   = (const float*)d_in[2];
    const int*   t0   = (const int*)d_in[3];
    const int*   t1   = (const int*)d_in[4];
    const int*   t2   = (const int*)d_in[5];
    const float* A0   = (const float*)d_in[6];
    const float* A1   = (const float*)d_in[7];
    const float* E0   = (const float*)d_in[8];
    const float* E1   = (const float*)d_in[9];
    const float* W_fe = (const float*)d_in[10];
    const float* b_fe = (const float*)d_in[11];
    const float* W_x  = (const float*)d_in[12];
    const float* W_h  = (const float*)d_in[13];
    const float* W_e  = (const float*)d_in[14];
    const float* W_g  = (const float*)d_in[15];
    const float* b_g  = (const float*)d_in[16];
    const float* b_r  = (const float*)d_in[17];
    float* out = (float*)d_out;

    // ws layout (floats): Wc[49152] | bb[384] | pooled1[4194304] | h1[4194304]
    //                     | pooled0[262144] | Wc2t(bf16 as 8192 f) | Wg1t(8192 f)
    float* ws      = (float*)d_ws;
    float* Wc      = ws;
    float* bb      = ws + 49152;
    float* pooled1 = ws + 49536;
    float* h1v     = pooled1 + 4194304;
    float* pooled0 = h1v + 4194304;
    unsigned short* Wc2t = (unsigned short*)(pooled0 + 262144);
    unsigned short* Wg1t = Wc2t + 16384;

    prep_kernel<<<dim3(3, 129), 128, 0, stream>>>(W_fe, b_fe, W_x, b_r, Wc, bb);
    prep_t_kernel<<<128, 128, 0, stream>>>(Wc + 2*16384, W_g + 16384, Wc2t, Wg1t);

    // fused level-2 + level-1 GNN (MFMA): x2 -> pooled1, no h2/Z round-trip
    hipFuncSetAttribute((const void*)leafz_kernel,
                        hipFuncAttributeMaxDynamicSharedMemorySize, SM_TOTAL);
    leafz_kernel<<<256, 512, SM_TOTAL, stream>>>(
        x2, t2, A1, E1, Wc2t, Wg1t,
        bb + 256, W_x + 2*WX_STRIDE + 16384, W_e + 8, b_g + 128,
        pooled1);

    rnn_kernel<8><<<32768/8, 64, 0, stream>>>(
        x1, t1, pooled1,
        Wc + 16384, W_h + 16384, bb + 128, W_x + WX_STRIDE + 16384,
        h1v);

    gnn_kernel<false><<<2048, 64, 0, stream>>>(
        h1v, nullptr, A0, E0,
        W_e, W_g, b_g,
        nullptr, nullptr, nullptr,
        pooled0);

    rnn_kernel<8><<<2048/8, 64, 0, stream>>>(
        x0, t0, pooled0,
        Wc, W_h, bb, W_x + 16384,
        out);
}